// Round 1
// baseline (362.921 us; speedup 1.0000x reference)
//
#include <hip/hip_runtime.h>
#include <hip/hip_cooperative_groups.h>

namespace cg = cooperative_groups;

#define VR 4
#define NVOX 64            // VR^3
#define NCLS 40
#define NB 64
#define NPTS 100000
#define BPB 16             // blocks per batch
#define NBLK (NB * BPB)    // 1024 blocks = 4 blocks/CU on 256 CUs (co-resident)
#define G_PER_B (NPTS / 4)        // 25000 groups of 4 points (= 3 float4 each)
#define F4_PER_B (NPTS * 3 / 4)   // 75000 float4 per batch
#define STRIDE_G (BPB * 256)      // 4096 groups per grid-stride step
#define FULL_ITERS (G_PER_B / STRIDE_G)            // 6 full (valid-everywhere) iters
#define TAIL_G (G_PER_B - FULL_ITERS * STRIDE_G)   // 424 ragged groups
#define FLT_BIG 3.402823466e38f

__device__ __forceinline__ int bin1(float v, float mn, float s4) {
    int i = (int)((v - mn) * s4);   // v>=mn, s4>0 -> trunc==floor
    return i > (VR - 1) ? (VR - 1) : i;
}

// lane L of the wave owns voxel L: AND of per-bit (ballot XOR lane-complement)
__device__ __forceinline__ unsigned long long vox_mask(
        int v, const unsigned long long* ns) {
    return (__ballot(v & 1)  ^ ns[0]) & (__ballot(v & 2)  ^ ns[1])
         & (__ballot(v & 4)  ^ ns[2]) & (__ballot(v & 8)  ^ ns[3])
         & (__ballot(v & 16) ^ ns[4]) & (__ballot(v & 32) ^ ns[5]);
}

__global__ __launch_bounds__(256, 4) void fused_k(
        const float4* __restrict__ x, const float* __restrict__ W,
        const float* __restrict__ bias, float* __restrict__ out,
        float* __restrict__ pmin, float* __restrict__ pmax,
        unsigned* __restrict__ phist) {
    const int b = blockIdx.x / BPB;
    const int sub = blockIdx.x % BPB;
    const float4* xb = x + (size_t)b * F4_PER_B;
    const int lane = threadIdx.x & 63;
    const int wv = threadIdx.x >> 6;
    const int t0 = sub * 256 + (int)threadIdx.x;

    __shared__ float sW[NCLS * NVOX];      // 10.25 KB (phase C, blocks < NB)
    __shared__ float smn[4][3], smx[4][3];
    __shared__ float smm[6];
    __shared__ unsigned swh[4][NVOX];
    __shared__ float fh[NVOX];

    // Blocks 0..NB-1 preload W for phase C; HBM latency hides under phase A.
    if (blockIdx.x < NB)
        for (int i = threadIdx.x; i < NCLS * NVOX; i += 256)
            sW[i] = W[i];

    // ---------------- Phase A: per-block per-dim min/max ----------------
    float mn0 = FLT_BIG, mn1 = FLT_BIG, mn2 = FLT_BIG;
    float mx0 = -FLT_BIG, mx1 = -FLT_BIG, mx2 = -FLT_BIG;
    #pragma unroll
    for (int k = 0; k < FULL_ITERS; k++) {
        const int g = t0 + k * STRIDE_G;
        float4 a = xb[3 * g];
        float4 c = xb[3 * g + 1];
        float4 e = xb[3 * g + 2];
        // flat%3: a.x->0 a.y->1 a.z->2 a.w->0 c.x->1 c.y->2
        //         c.z->0 c.w->1 e.x->2 e.y->0 e.z->1 e.w->2
        mn0 = fminf(mn0, fminf(fminf(a.x, a.w), fminf(c.z, e.y)));
        mx0 = fmaxf(mx0, fmaxf(fmaxf(a.x, a.w), fmaxf(c.z, e.y)));
        mn1 = fminf(mn1, fminf(fminf(a.y, c.x), fminf(c.w, e.z)));
        mx1 = fmaxf(mx1, fmaxf(fmaxf(a.y, c.x), fmaxf(c.w, e.z)));
        mn2 = fminf(mn2, fminf(fminf(a.z, c.y), fminf(e.x, e.w)));
        mx2 = fmaxf(mx2, fmaxf(fmaxf(a.z, c.y), fmaxf(e.x, e.w)));
    }
    if (sub * 256 < TAIL_G && t0 < TAIL_G) {   // only subs 0,1 touch the tail
        const int g = FULL_ITERS * STRIDE_G + t0;
        float4 a = xb[3 * g];
        float4 c = xb[3 * g + 1];
        float4 e = xb[3 * g + 2];
        mn0 = fminf(mn0, fminf(fminf(a.x, a.w), fminf(c.z, e.y)));
        mx0 = fmaxf(mx0, fmaxf(fmaxf(a.x, a.w), fmaxf(c.z, e.y)));
        mn1 = fminf(mn1, fminf(fminf(a.y, c.x), fminf(c.w, e.z)));
        mx1 = fmaxf(mx1, fmaxf(fmaxf(a.y, c.x), fmaxf(c.w, e.z)));
        mn2 = fminf(mn2, fminf(fminf(a.z, c.y), fminf(e.x, e.w)));
        mx2 = fmaxf(mx2, fmaxf(fmaxf(a.z, c.y), fmaxf(e.x, e.w)));
    }

    #pragma unroll
    for (int off = 32; off > 0; off >>= 1) {
        mn0 = fminf(mn0, __shfl_down(mn0, off, 64));
        mn1 = fminf(mn1, __shfl_down(mn1, off, 64));
        mn2 = fminf(mn2, __shfl_down(mn2, off, 64));
        mx0 = fmaxf(mx0, __shfl_down(mx0, off, 64));
        mx1 = fmaxf(mx1, __shfl_down(mx1, off, 64));
        mx2 = fmaxf(mx2, __shfl_down(mx2, off, 64));
    }
    if (lane == 0) {
        smn[wv][0] = mn0; smn[wv][1] = mn1; smn[wv][2] = mn2;
        smx[wv][0] = mx0; smx[wv][1] = mx1; smx[wv][2] = mx2;
    }
    __syncthreads();
    if (threadIdx.x < 3) {
        const int d = threadIdx.x;
        float a = smn[0][d], z = smx[0][d];
        #pragma unroll
        for (int w = 1; w < 4; w++) {
            a = fminf(a, smn[w][d]);
            z = fmaxf(z, smx[w][d]);
        }
        pmin[(b * BPB + sub) * 3 + d] = a;
        pmax[(b * BPB + sub) * 3 + d] = z;
    }

    cg::this_grid().sync();

    // ---------------- Phase B: ballot-count histogram ----------------
    if (threadIdx.x < 6) {
        const int d = threadIdx.x % 3;
        const bool isMax = threadIdx.x >= 3;
        float r = isMax ? -FLT_BIG : FLT_BIG;
        for (int s = 0; s < BPB; s++) {
            float v = isMax ? pmax[(b * BPB + s) * 3 + d]
                            : pmin[(b * BPB + s) * 3 + d];
            r = isMax ? fmaxf(r, v) : fminf(r, v);
        }
        smm[threadIdx.x] = r;
    }
    __syncthreads();
    const float bn0 = smm[0], bn1 = smm[1], bn2 = smm[2];
    const float s40 = (float)VR / (smm[3] - smm[0]);
    const float s41 = (float)VR / (smm[4] - smm[1]);
    const float s42 = (float)VR / (smm[5] - smm[2]);

    unsigned long long ns[6];
    #pragma unroll
    for (int k = 0; k < 6; k++)
        ns[k] = ((lane >> k) & 1) ? 0ull : ~0ull;

    unsigned cnt = 0;
    #pragma unroll 2
    for (int k = 0; k < FULL_ITERS; k++) {   // all lanes valid: no mask needed
        const int g = t0 + k * STRIDE_G;
        float4 a = xb[3 * g];
        float4 c = xb[3 * g + 1];
        float4 e = xb[3 * g + 2];
        int v0 = bin1(a.x, bn0, s40) * 16 + bin1(a.y, bn1, s41) * 4 + bin1(a.z, bn2, s42);
        int v1 = bin1(a.w, bn0, s40) * 16 + bin1(c.x, bn1, s41) * 4 + bin1(c.y, bn2, s42);
        int v2 = bin1(c.z, bn0, s40) * 16 + bin1(c.w, bn1, s41) * 4 + bin1(e.x, bn2, s42);
        int v3 = bin1(e.y, bn0, s40) * 16 + bin1(e.z, bn1, s41) * 4 + bin1(e.w, bn2, s42);
        cnt += (unsigned)__popcll(vox_mask(v0, ns));
        cnt += (unsigned)__popcll(vox_mask(v1, ns));
        cnt += (unsigned)__popcll(vox_mask(v2, ns));
        cnt += (unsigned)__popcll(vox_mask(v3, ns));
    }
    if (sub * 256 < TAIL_G) {               // ragged tail: subs 0,1 only
        const bool valid = t0 < TAIL_G;
        const unsigned long long vm = __ballot(valid);
        const int g = FULL_ITERS * STRIDE_G + (valid ? t0 : 0);
        float4 a = xb[3 * g];
        float4 c = xb[3 * g + 1];
        float4 e = xb[3 * g + 2];
        int v0 = bin1(a.x, bn0, s40) * 16 + bin1(a.y, bn1, s41) * 4 + bin1(a.z, bn2, s42);
        int v1 = bin1(a.w, bn0, s40) * 16 + bin1(c.x, bn1, s41) * 4 + bin1(c.y, bn2, s42);
        int v2 = bin1(c.z, bn0, s40) * 16 + bin1(c.w, bn1, s41) * 4 + bin1(e.x, bn2, s42);
        int v3 = bin1(e.y, bn0, s40) * 16 + bin1(e.z, bn1, s41) * 4 + bin1(e.w, bn2, s42);
        cnt += (unsigned)__popcll(vm & vox_mask(v0, ns));
        cnt += (unsigned)__popcll(vm & vox_mask(v1, ns));
        cnt += (unsigned)__popcll(vm & vox_mask(v2, ns));
        cnt += (unsigned)__popcll(vm & vox_mask(v3, ns));
    }

    swh[wv][lane] = cnt;
    __syncthreads();
    if (threadIdx.x < NVOX)
        phist[(b * BPB + sub) * NVOX + threadIdx.x] =
            swh[0][threadIdx.x] + swh[1][threadIdx.x] +
            swh[2][threadIdx.x] + swh[3][threadIdx.x];

    cg::this_grid().sync();

    // ---------------- Phase C: partial reduce + GEMV (blocks 0..NB-1) ----
    if (blockIdx.x >= NB) return;
    {
        const int vox = threadIdx.x & 63;
        const int part = threadIdx.x >> 6;     // 0..3, each sums 4 partials
        unsigned s = 0;
        #pragma unroll
        for (int p = 0; p < 4; p++)
            s += phist[(blockIdx.x * BPB + part * 4 + p) * NVOX + vox];
        swh[part][vox] = s;                    // safe: block-local reuse after sync
    }
    __syncthreads();
    if (threadIdx.x < NVOX)
        fh[threadIdx.x] = (float)(swh[0][threadIdx.x] + swh[1][threadIdx.x] +
                                  swh[2][threadIdx.x] + swh[3][threadIdx.x])
                          * (1.0f / (float)NPTS);
    __syncthreads();
    if (threadIdx.x < NCLS) {
        float acc = 0.f;
        #pragma unroll
        for (int f = 0; f < NVOX; f++)
            acc += fh[f] * sW[threadIdx.x * NVOX + f];
        out[blockIdx.x * NCLS + threadIdx.x] = acc + bias[threadIdx.x];
    }
}

extern "C" void kernel_launch(void* const* d_in, const int* in_sizes, int n_in,
                              void* d_out, int out_size, void* d_ws, size_t ws_size,
                              hipStream_t stream) {
    const float4* x = (const float4*)d_in[0];    // (64, 100000, 3) fp32
    const float* W = (const float*)d_in[1];      // (40, 64) fp32
    const float* bias = (const float*)d_in[2];   // (40,) fp32
    float* out = (float*)d_out;                  // (64, 40) fp32

    // ws layout (every slot fully overwritten every call -> no init needed):
    //   pmin  : NBLK*3 f32
    //   pmax  : NBLK*3 f32
    //   phist : NBLK*64 u32
    float* pmin = (float*)d_ws;
    float* pmax = pmin + NBLK * 3;
    unsigned* phist = (unsigned*)(pmax + NBLK * 3);

    void* args[] = {(void*)&x, (void*)&W, (void*)&bias, (void*)&out,
                    (void*)&pmin, (void*)&pmax, (void*)&phist};
    hipLaunchCooperativeKernel((const void*)fused_k, dim3(NBLK), dim3(256),
                               args, 0, stream);
}

// Round 3
// 128.342 us; speedup vs baseline: 2.8278x; 2.8278x over previous
//
#include <hip/hip_runtime.h>

#define VR 4
#define NVOX 64            // VR^3
#define NCLS 40
#define NB 64
#define NPTS 100000
#define BPB 16             // blocks per batch
#define NBLK (NB * BPB)
#define G_PER_B (NPTS / 4)        // 25000 groups of 4 points (= 3 float4 each)
#define F4_PER_B (NPTS * 3 / 4)   // 75000 float4 per batch
#define STRIDE_G (BPB * 256)      // 4096 groups per step
#define FULL_ITERS (G_PER_B / STRIDE_G)            // 6 full (all-valid) iters
#define TAIL_G (G_PER_B - FULL_ITERS * STRIDE_G)   // 424 ragged groups
#define FLT_BIG 3.402823466e38f

static __device__ __forceinline__ int bin1(float v, float mn, float s4) {
    int i = (int)((v - mn) * s4);   // v>=mn, s4>0 -> trunc==floor
    return i > (VR - 1) ? (VR - 1) : i;
}

// lane L of the wave owns voxel L: AND of per-bit (ballot XOR lane-complement)
static __device__ __forceinline__ unsigned long long vox_mask(
        int v, const unsigned long long* ns) {
    return (__ballot(v & 1)  ^ ns[0]) & (__ballot(v & 2)  ^ ns[1])
         & (__ballot(v & 4)  ^ ns[2]) & (__ballot(v & 8)  ^ ns[3])
         & (__ballot(v & 16) ^ ns[4]) & (__ballot(v & 32) ^ ns[5]);
}

// ---------------------------------------------------------------------------
// Kernel 1: per-block per-dim min/max partials. Pure HBM stream (~77 MB).
// Every partial slot unconditionally written -> no init needed.
// ---------------------------------------------------------------------------
__global__ __launch_bounds__(256) void minmax_k(const float4* __restrict__ x,
                                                float* __restrict__ pmin,
                                                float* __restrict__ pmax) {
    const int b = blockIdx.x / BPB;
    const int sub = blockIdx.x % BPB;
    const float4* xb = x + (size_t)b * F4_PER_B;
    const int lane = threadIdx.x & 63;
    const int wv = threadIdx.x >> 6;
    const int t0 = sub * 256 + (int)threadIdx.x;

    float mn0 = FLT_BIG, mn1 = FLT_BIG, mn2 = FLT_BIG;
    float mx0 = -FLT_BIG, mx1 = -FLT_BIG, mx2 = -FLT_BIG;
    #pragma unroll
    for (int k = 0; k < FULL_ITERS; k++) {         // no predication in hot loop
        const int g = t0 + k * STRIDE_G;
        const float4 a = xb[3 * g], c = xb[3 * g + 1], e = xb[3 * g + 2];
        // flat%3: a.x->0 a.y->1 a.z->2 a.w->0 c.x->1 c.y->2
        //         c.z->0 c.w->1 e.x->2 e.y->0 e.z->1 e.w->2
        mn0 = fminf(mn0, fminf(fminf(a.x, a.w), fminf(c.z, e.y)));
        mx0 = fmaxf(mx0, fmaxf(fmaxf(a.x, a.w), fmaxf(c.z, e.y)));
        mn1 = fminf(mn1, fminf(fminf(a.y, c.x), fminf(c.w, e.z)));
        mx1 = fmaxf(mx1, fmaxf(fmaxf(a.y, c.x), fmaxf(c.w, e.z)));
        mn2 = fminf(mn2, fminf(fminf(a.z, c.y), fminf(e.x, e.w)));
        mx2 = fmaxf(mx2, fmaxf(fmaxf(a.z, c.y), fmaxf(e.x, e.w)));
    }
    if (sub * 256 < TAIL_G && t0 < TAIL_G) {       // ragged tail: subs 0,1 only
        const int g = FULL_ITERS * STRIDE_G + t0;
        const float4 a = xb[3 * g], c = xb[3 * g + 1], e = xb[3 * g + 2];
        mn0 = fminf(mn0, fminf(fminf(a.x, a.w), fminf(c.z, e.y)));
        mx0 = fmaxf(mx0, fmaxf(fmaxf(a.x, a.w), fmaxf(c.z, e.y)));
        mn1 = fminf(mn1, fminf(fminf(a.y, c.x), fminf(c.w, e.z)));
        mx1 = fmaxf(mx1, fmaxf(fmaxf(a.y, c.x), fmaxf(c.w, e.z)));
        mn2 = fminf(mn2, fminf(fminf(a.z, c.y), fminf(e.x, e.w)));
        mx2 = fmaxf(mx2, fmaxf(fmaxf(a.z, c.y), fmaxf(e.x, e.w)));
    }

    #pragma unroll
    for (int off = 32; off > 0; off >>= 1) {
        mn0 = fminf(mn0, __shfl_down(mn0, off, 64));
        mn1 = fminf(mn1, __shfl_down(mn1, off, 64));
        mn2 = fminf(mn2, __shfl_down(mn2, off, 64));
        mx0 = fmaxf(mx0, __shfl_down(mx0, off, 64));
        mx1 = fmaxf(mx1, __shfl_down(mx1, off, 64));
        mx2 = fmaxf(mx2, __shfl_down(mx2, off, 64));
    }

    __shared__ float smn[4][3], smx[4][3];
    if (lane == 0) {
        smn[wv][0] = mn0; smn[wv][1] = mn1; smn[wv][2] = mn2;
        smx[wv][0] = mx0; smx[wv][1] = mx1; smx[wv][2] = mx2;
    }
    __syncthreads();
    if (threadIdx.x < 3) {
        const int d = threadIdx.x;
        float a = smn[0][d], z = smx[0][d];
        #pragma unroll
        for (int w = 1; w < 4; w++) {
            a = fminf(a, smn[w][d]);
            z = fmaxf(z, smx[w][d]);
        }
        pmin[(b * BPB + sub) * 3 + d] = a;
        pmax[(b * BPB + sub) * 3 + d] = z;
    }
}

// ---------------------------------------------------------------------------
// Kernel 2: ballot-count histogram (x is L3-hot) + fused partial GEMV.
// out[b] = sum over 16 blocks of (partial_hist/N)·W^T, via device atomicAdd
// (coherent by default; end-of-kernel flush guarantees final visibility).
// No phist buffer, no third kernel, no custom sync.
// ---------------------------------------------------------------------------
__global__ __launch_bounds__(256) void hist_gemv_k(const float4* __restrict__ x,
                                                   const float* __restrict__ pmin,
                                                   const float* __restrict__ pmax,
                                                   const float* __restrict__ W,
                                                   const float* __restrict__ bias,
                                                   float* __restrict__ out) {
    const int b = blockIdx.x / BPB;
    const int sub = blockIdx.x % BPB;
    const float4* xb = x + (size_t)b * F4_PER_B;
    const int lane = threadIdx.x & 63;
    const int wv = threadIdx.x >> 6;
    const int t0 = sub * 256 + (int)threadIdx.x;

    __shared__ float sW[NCLS * NVOX];   // 10.25 KB; load overlaps hist loop
    __shared__ float smm[6];            // mn0 mn1 mn2 mx0 mx1 mx2
    __shared__ unsigned swh[4][NVOX];
    __shared__ float fh[NVOX];

    for (int i = threadIdx.x; i < NCLS * NVOX; i += 256)
        sW[i] = W[i];

    if (threadIdx.x < 6) {              // reduce the 16 min/max partials
        const int d = threadIdx.x % 3;
        const bool isMax = threadIdx.x >= 3;
        float r = isMax ? -FLT_BIG : FLT_BIG;
        for (int s = 0; s < BPB; s++) {
            float v = isMax ? pmax[(b * BPB + s) * 3 + d]
                            : pmin[(b * BPB + s) * 3 + d];
            r = isMax ? fmaxf(r, v) : fminf(r, v);
        }
        smm[threadIdx.x] = r;
    }
    __syncthreads();
    const float bn0 = smm[0], bn1 = smm[1], bn2 = smm[2];
    const float s40 = (float)VR / (smm[3] - smm[0]);
    const float s41 = (float)VR / (smm[4] - smm[1]);
    const float s42 = (float)VR / (smm[5] - smm[2]);

    unsigned long long ns[6];
    #pragma unroll
    for (int k = 0; k < 6; k++)
        ns[k] = ((lane >> k) & 1) ? 0ull : ~0ull;

    unsigned cnt = 0;
    #pragma unroll 2
    for (int k = 0; k < FULL_ITERS; k++) {         // all lanes valid: no mask
        const int g = t0 + k * STRIDE_G;
        const float4 a = xb[3 * g], c = xb[3 * g + 1], e = xb[3 * g + 2];
        int v0 = bin1(a.x, bn0, s40) * 16 + bin1(a.y, bn1, s41) * 4 + bin1(a.z, bn2, s42);
        int v1 = bin1(a.w, bn0, s40) * 16 + bin1(c.x, bn1, s41) * 4 + bin1(c.y, bn2, s42);
        int v2 = bin1(c.z, bn0, s40) * 16 + bin1(c.w, bn1, s41) * 4 + bin1(e.x, bn2, s42);
        int v3 = bin1(e.y, bn0, s40) * 16 + bin1(e.z, bn1, s41) * 4 + bin1(e.w, bn2, s42);
        cnt += (unsigned)__popcll(vox_mask(v0, ns));
        cnt += (unsigned)__popcll(vox_mask(v1, ns));
        cnt += (unsigned)__popcll(vox_mask(v2, ns));
        cnt += (unsigned)__popcll(vox_mask(v3, ns));
    }
    if (sub * 256 < TAIL_G) {                      // ragged tail: subs 0,1 only
        const bool valid = t0 < TAIL_G;
        const unsigned long long vm = __ballot(valid);
        const int g = FULL_ITERS * STRIDE_G + (valid ? t0 : 0);
        const float4 a = xb[3 * g], c = xb[3 * g + 1], e = xb[3 * g + 2];
        int v0 = bin1(a.x, bn0, s40) * 16 + bin1(a.y, bn1, s41) * 4 + bin1(a.z, bn2, s42);
        int v1 = bin1(a.w, bn0, s40) * 16 + bin1(c.x, bn1, s41) * 4 + bin1(c.y, bn2, s42);
        int v2 = bin1(c.z, bn0, s40) * 16 + bin1(c.w, bn1, s41) * 4 + bin1(e.x, bn2, s42);
        int v3 = bin1(e.y, bn0, s40) * 16 + bin1(e.z, bn1, s41) * 4 + bin1(e.w, bn2, s42);
        cnt += (unsigned)__popcll(vm & vox_mask(v0, ns));
        cnt += (unsigned)__popcll(vm & vox_mask(v1, ns));
        cnt += (unsigned)__popcll(vm & vox_mask(v2, ns));
        cnt += (unsigned)__popcll(vm & vox_mask(v3, ns));
    }

    swh[wv][lane] = cnt;
    __syncthreads();
    if (threadIdx.x < NVOX)
        fh[threadIdx.x] = (float)(swh[0][threadIdx.x] + swh[1][threadIdx.x] +
                                  swh[2][threadIdx.x] + swh[3][threadIdx.x])
                          * (1.0f / (float)NPTS);
    __syncthreads();
    if (threadIdx.x < NCLS) {                      // partial GEMV + atomic sum
        const int c = threadIdx.x;
        float acc = (sub == 0) ? bias[c] : 0.f;
        #pragma unroll
        for (int f = 0; f < NVOX; f++)
            acc += fh[f] * sW[c * NVOX + f];
        atomicAdd(&out[b * NCLS + c], acc);
    }
}

extern "C" void kernel_launch(void* const* d_in, const int* in_sizes, int n_in,
                              void* d_out, int out_size, void* d_ws, size_t ws_size,
                              hipStream_t stream) {
    const float4* x = (const float4*)d_in[0];    // (64, 100000, 3) fp32
    const float* W = (const float*)d_in[1];      // (40, 64) fp32
    const float* bias = (const float*)d_in[2];   // (40,) fp32
    float* out = (float*)d_out;                  // (64, 40) fp32

    // ws layout: pmin NBLK*3 f32 | pmax NBLK*3 f32 (fully rewritten per call)
    float* pmin = (float*)d_ws;
    float* pmax = pmin + NBLK * 3;

    // out accumulates via atomicAdd -> must be zeroed every launch (the
    // timing loop does not re-zero it between replays).
    hipMemsetAsync(out, 0, NB * NCLS * sizeof(float), stream);

    minmax_k<<<NBLK, 256, 0, stream>>>(x, pmin, pmax);
    hist_gemv_k<<<NBLK, 256, 0, stream>>>(x, pmin, pmax, W, bias, out);
}

// Round 5
// 127.233 us; speedup vs baseline: 2.8524x; 1.0087x over previous
//
#include <hip/hip_runtime.h>

#define VR 4
#define NVOX 64            // VR^3
#define NCLS 40
#define NB 64
#define NPTS 100000
#define BPB 16             // blocks per batch
#define NBLK (NB * BPB)
#define G_PER_B (NPTS / 4)        // 25000 groups of 4 points (= 3 float4 each)
#define F4_PER_B (NPTS * 3 / 4)   // 75000 float4 per batch
#define STRIDE_G (BPB * 256)      // 4096 groups per step
#define FULL_ITERS (G_PER_B / STRIDE_G)            // 6 full (all-valid) iters
#define TAIL_G (G_PER_B - FULL_ITERS * STRIDE_G)   // 424 ragged groups
#define FLT_BIG 3.402823466e38f

static __device__ __forceinline__ int bin1(float v, float mn, float s4) {
    int i = (int)((v - mn) * s4);   // v>=mn, s4>0 -> trunc==floor
    return i > (VR - 1) ? (VR - 1) : i;
}

// lane L of the wave owns voxel L: AND of per-bit (ballot XOR lane-complement)
static __device__ __forceinline__ unsigned long long vox_mask(
        int v, const unsigned long long* ns) {
    return (__ballot(v & 1)  ^ ns[0]) & (__ballot(v & 2)  ^ ns[1])
         & (__ballot(v & 4)  ^ ns[2]) & (__ballot(v & 8)  ^ ns[3])
         & (__ballot(v & 16) ^ ns[4]) & (__ballot(v & 32) ^ ns[5]);
}

// ---------------------------------------------------------------------------
// Kernel 1: per-block per-dim min/max partials (pure ~77 MB HBM stream).
// sub==0 blocks also zero out[b] (plain stores; ordered before kernel 2 by
// the kernel boundary) so no separate memset dispatch is needed.
// ---------------------------------------------------------------------------
__global__ __launch_bounds__(256) void minmax_k(const float4* __restrict__ x,
                                                float* __restrict__ pmin,
                                                float* __restrict__ pmax,
                                                float* __restrict__ out) {
    const int b = blockIdx.x / BPB;
    const int sub = blockIdx.x % BPB;
    const float4* xb = x + (size_t)b * F4_PER_B;
    const int lane = threadIdx.x & 63;
    const int wv = threadIdx.x >> 6;
    const int t0 = sub * 256 + (int)threadIdx.x;

    if (sub == 0 && threadIdx.x < NCLS)   // zero the atomic accumulator
        out[b * NCLS + threadIdx.x] = 0.f;

    float mn0 = FLT_BIG, mn1 = FLT_BIG, mn2 = FLT_BIG;
    float mx0 = -FLT_BIG, mx1 = -FLT_BIG, mx2 = -FLT_BIG;
    #pragma unroll
    for (int k = 0; k < FULL_ITERS; k++) {         // no predication in hot loop
        const int g = t0 + k * STRIDE_G;
        const float4 a = xb[3 * g], c = xb[3 * g + 1], e = xb[3 * g + 2];
        // flat%3: a.x->0 a.y->1 a.z->2 a.w->0 c.x->1 c.y->2
        //         c.z->0 c.w->1 e.x->2 e.y->0 e.z->1 e.w->2
        mn0 = fminf(mn0, fminf(fminf(a.x, a.w), fminf(c.z, e.y)));
        mx0 = fmaxf(mx0, fmaxf(fmaxf(a.x, a.w), fmaxf(c.z, e.y)));
        mn1 = fminf(mn1, fminf(fminf(a.y, c.x), fminf(c.w, e.z)));
        mx1 = fmaxf(mx1, fmaxf(fmaxf(a.y, c.x), fmaxf(c.w, e.z)));
        mn2 = fminf(mn2, fminf(fminf(a.z, c.y), fminf(e.x, e.w)));
        mx2 = fmaxf(mx2, fmaxf(fmaxf(a.z, c.y), fmaxf(e.x, e.w)));
    }
    if (sub * 256 < TAIL_G && t0 < TAIL_G) {       // ragged tail: subs 0,1 only
        const int g = FULL_ITERS * STRIDE_G + t0;
        const float4 a = xb[3 * g], c = xb[3 * g + 1], e = xb[3 * g + 2];
        mn0 = fminf(mn0, fminf(fminf(a.x, a.w), fminf(c.z, e.y)));
        mx0 = fmaxf(mx0, fmaxf(fmaxf(a.x, a.w), fmaxf(c.z, e.y)));
        mn1 = fminf(mn1, fminf(fminf(a.y, c.x), fminf(c.w, e.z)));
        mx1 = fmaxf(mx1, fmaxf(fmaxf(a.y, c.x), fmaxf(c.w, e.z)));
        mn2 = fminf(mn2, fminf(fminf(a.z, c.y), fminf(e.x, e.w)));
        mx2 = fmaxf(mx2, fmaxf(fmaxf(a.z, c.y), fmaxf(e.x, e.w)));
    }

    #pragma unroll
    for (int off = 32; off > 0; off >>= 1) {
        mn0 = fminf(mn0, __shfl_down(mn0, off, 64));
        mn1 = fminf(mn1, __shfl_down(mn1, off, 64));
        mn2 = fminf(mn2, __shfl_down(mn2, off, 64));
        mx0 = fmaxf(mx0, __shfl_down(mx0, off, 64));
        mx1 = fmaxf(mx1, __shfl_down(mx1, off, 64));
        mx2 = fmaxf(mx2, __shfl_down(mx2, off, 64));
    }

    __shared__ float smn[4][3], smx[4][3];
    if (lane == 0) {
        smn[wv][0] = mn0; smn[wv][1] = mn1; smn[wv][2] = mn2;
        smx[wv][0] = mx0; smx[wv][1] = mx1; smx[wv][2] = mx2;
    }
    __syncthreads();
    if (threadIdx.x < 3) {
        const int d = threadIdx.x;
        float a = smn[0][d], z = smx[0][d];
        #pragma unroll
        for (int w = 1; w < 4; w++) {
            a = fminf(a, smn[w][d]);
            z = fmaxf(z, smx[w][d]);
        }
        pmin[(b * BPB + sub) * 3 + d] = a;
        pmax[(b * BPB + sub) * 3 + d] = z;
    }
}

// ---------------------------------------------------------------------------
// Kernel 2: ballot-count histogram (x is L3-hot) + fused partial GEMV.
// out[b] = sum over 16 blocks of (partial_hist/N)·W^T via device atomicAdd
// (device-coherent by default; end-of-kernel flush guarantees visibility).
// ---------------------------------------------------------------------------
__global__ __launch_bounds__(256) void hist_gemv_k(const float4* __restrict__ x,
                                                   const float* __restrict__ pmin,
                                                   const float* __restrict__ pmax,
                                                   const float* __restrict__ W,
                                                   const float* __restrict__ bias,
                                                   float* __restrict__ out) {
    const int b = blockIdx.x / BPB;
    const int sub = blockIdx.x % BPB;
    const float4* xb = x + (size_t)b * F4_PER_B;
    const int lane = threadIdx.x & 63;
    const int wv = threadIdx.x >> 6;
    const int t0 = sub * 256 + (int)threadIdx.x;

    __shared__ float sW[NVOX * NCLS];   // TRANSPOSED [f][c]: GEMV conflict-free
    __shared__ float smm[6];            // mn0 mn1 mn2 mx0 mx1 mx2
    __shared__ unsigned swh[4][NVOX];
    __shared__ float fh[NVOX];

    for (int i = threadIdx.x; i < NCLS * NVOX; i += 256)   // overlaps hist loop
        sW[(i % NVOX) * NCLS + (i / NVOX)] = W[i];

    if (threadIdx.x < 6) {              // reduce the 16 min/max partials
        const int d = threadIdx.x % 3;
        const bool isMax = threadIdx.x >= 3;
        float r = isMax ? -FLT_BIG : FLT_BIG;
        for (int s = 0; s < BPB; s++) {
            float v = isMax ? pmax[(b * BPB + s) * 3 + d]
                            : pmin[(b * BPB + s) * 3 + d];
            r = isMax ? fmaxf(r, v) : fminf(r, v);
        }
        smm[threadIdx.x] = r;
    }
    __syncthreads();
    const float bn0 = smm[0], bn1 = smm[1], bn2 = smm[2];
    const float s40 = (float)VR / (smm[3] - smm[0]);
    const float s41 = (float)VR / (smm[4] - smm[1]);
    const float s42 = (float)VR / (smm[5] - smm[2]);

    unsigned long long ns[6];
    #pragma unroll
    for (int k = 0; k < 6; k++)
        ns[k] = ((lane >> k) & 1) ? 0ull : ~0ull;

    unsigned cnt = 0;
    #pragma unroll 2
    for (int k = 0; k < FULL_ITERS; k++) {         // all lanes valid: no mask
        const int g = t0 + k * STRIDE_G;
        const float4 a = xb[3 * g], c = xb[3 * g + 1], e = xb[3 * g + 2];
        int v0 = bin1(a.x, bn0, s40) * 16 + bin1(a.y, bn1, s41) * 4 + bin1(a.z, bn2, s42);
        int v1 = bin1(a.w, bn0, s40) * 16 + bin1(c.x, bn1, s41) * 4 + bin1(c.y, bn2, s42);
        int v2 = bin1(c.z, bn0, s40) * 16 + bin1(c.w, bn1, s41) * 4 + bin1(e.x, bn2, s42);
        int v3 = bin1(e.y, bn0, s40) * 16 + bin1(e.z, bn1, s41) * 4 + bin1(e.w, bn2, s42);
        cnt += (unsigned)__popcll(vox_mask(v0, ns));
        cnt += (unsigned)__popcll(vox_mask(v1, ns));
        cnt += (unsigned)__popcll(vox_mask(v2, ns));
        cnt += (unsigned)__popcll(vox_mask(v3, ns));
    }
    if (sub * 256 < TAIL_G) {                      // ragged tail: subs 0,1 only
        const bool valid = t0 < TAIL_G;
        const unsigned long long vm = __ballot(valid);
        const int g = FULL_ITERS * STRIDE_G + (valid ? t0 : 0);
        const float4 a = xb[3 * g], c = xb[3 * g + 1], e = xb[3 * g + 2];
        int v0 = bin1(a.x, bn0, s40) * 16 + bin1(a.y, bn1, s41) * 4 + bin1(a.z, bn2, s42);
        int v1 = bin1(a.w, bn0, s40) * 16 + bin1(c.x, bn1, s41) * 4 + bin1(c.y, bn2, s42);
        int v2 = bin1(c.z, bn0, s40) * 16 + bin1(c.w, bn1, s41) * 4 + bin1(e.x, bn2, s42);
        int v3 = bin1(e.y, bn0, s40) * 16 + bin1(e.z, bn1, s41) * 4 + bin1(e.w, bn2, s42);
        cnt += (unsigned)__popcll(vm & vox_mask(v0, ns));
        cnt += (unsigned)__popcll(vm & vox_mask(v1, ns));
        cnt += (unsigned)__popcll(vm & vox_mask(v2, ns));
        cnt += (unsigned)__popcll(vm & vox_mask(v3, ns));
    }

    swh[wv][lane] = cnt;
    __syncthreads();
    if (threadIdx.x < NVOX)
        fh[threadIdx.x] = (float)(swh[0][threadIdx.x] + swh[1][threadIdx.x] +
                                  swh[2][threadIdx.x] + swh[3][threadIdx.x])
                          * (1.0f / (float)NPTS);
    __syncthreads();
    if (threadIdx.x < NCLS) {                      // partial GEMV + atomic sum
        const int c = threadIdx.x;
        float acc = (sub == 0) ? bias[c] : 0.f;
        #pragma unroll
        for (int f = 0; f < NVOX; f++)
            acc += fh[f] * sW[f * NCLS + c];       // transposed: conflict-free
        atomicAdd(&out[b * NCLS + c], acc);
    }
}

extern "C" void kernel_launch(void* const* d_in, const int* in_sizes, int n_in,
                              void* d_out, int out_size, void* d_ws, size_t ws_size,
                              hipStream_t stream) {
    const float4* x = (const float4*)d_in[0];    // (64, 100000, 3) fp32
    const float* W = (const float*)d_in[1];      // (40, 64) fp32
    const float* bias = (const float*)d_in[2];   // (40,) fp32
    float* out = (float*)d_out;                  // (64, 40) fp32

    // ws layout: pmin NBLK*3 f32 | pmax NBLK*3 f32 (fully rewritten per call)
    float* pmin = (float*)d_ws;
    float* pmax = pmin + NBLK * 3;

    minmax_k<<<NBLK, 256, 0, stream>>>(x, pmin, pmax, out);
    hist_gemv_k<<<NBLK, 256, 0, stream>>>(x, pmin, pmax, W, bias, out);
}

// Round 6
// 120.939 us; speedup vs baseline: 3.0008x; 1.0520x over previous
//
#include <hip/hip_runtime.h>

#define VR 4
#define NVOX 64            // VR^3
#define NCLS 40
#define NB 64
#define NPTS 100000
#define BPB 16             // blocks per batch
#define NBLK (NB * BPB)
#define G_PER_B (NPTS / 4)        // 25000 groups of 4 points (= 3 float4 each)
#define F4_PER_B (NPTS * 3 / 4)   // 75000 float4 per batch
#define STRIDE_G (BPB * 256)      // 4096 groups per step
#define FULL_ITERS (G_PER_B / STRIDE_G)            // 6 full (all-valid) iters
#define TAIL_G (G_PER_B - FULL_ITERS * STRIDE_G)   // 424 ragged groups
#define SW_LD 41                  // padded leading dim for transposed W in LDS
#define FLT_BIG 3.402823466e38f

static __device__ __forceinline__ int bin1(float v, float mn, float s4) {
    int i = (int)((v - mn) * s4);   // v>=mn, s4>0 -> trunc==floor
    return i > (VR - 1) ? (VR - 1) : i;
}

// lane L of the wave owns voxel L: AND of per-bit (ballot XOR lane-complement)
static __device__ __forceinline__ unsigned long long vox_mask(
        int v, const unsigned long long* ns) {
    return (__ballot(v & 1)  ^ ns[0]) & (__ballot(v & 2)  ^ ns[1])
         & (__ballot(v & 4)  ^ ns[2]) & (__ballot(v & 8)  ^ ns[3])
         & (__ballot(v & 16) ^ ns[4]) & (__ballot(v & 32) ^ ns[5]);
}

// ---------------------------------------------------------------------------
// Block labeling (BOTH kernels): b = bid & 63, sub = bid >> 6.
// With round-robin bid->XCD (bid % 8), all 16 blocks of batch b sit on
// XCD b%8 in BOTH launches -> k2 re-reads k1's lines from the same L2.
// Pure bijective relabel: correctness-independent, locality heuristic only.
// ---------------------------------------------------------------------------

// ---------------------------------------------------------------------------
// Kernel 1: per-block per-dim min/max partials (pure ~77 MB HBM stream).
// sub==0 blocks also zero out[b] (ordered before k2 by the kernel boundary).
// ---------------------------------------------------------------------------
__global__ __launch_bounds__(256) void minmax_k(const float4* __restrict__ x,
                                                float* __restrict__ pmin,
                                                float* __restrict__ pmax,
                                                float* __restrict__ out) {
    const int bid = blockIdx.x;
    const int b = bid & (NB - 1);
    const int sub = bid >> 6;
    const float4* xb = x + (size_t)b * F4_PER_B;
    const int lane = threadIdx.x & 63;
    const int wv = threadIdx.x >> 6;
    const int t0 = sub * 256 + (int)threadIdx.x;

    if (sub == 0 && threadIdx.x < NCLS)   // zero the atomic accumulator
        out[b * NCLS + threadIdx.x] = 0.f;

    float mn0 = FLT_BIG, mn1 = FLT_BIG, mn2 = FLT_BIG;
    float mx0 = -FLT_BIG, mx1 = -FLT_BIG, mx2 = -FLT_BIG;
    #pragma unroll
    for (int k = 0; k < FULL_ITERS; k++) {         // no predication in hot loop
        const int g = t0 + k * STRIDE_G;
        const float4 a = xb[3 * g], c = xb[3 * g + 1], e = xb[3 * g + 2];
        // flat%3: a.x->0 a.y->1 a.z->2 a.w->0 c.x->1 c.y->2
        //         c.z->0 c.w->1 e.x->2 e.y->0 e.z->1 e.w->2
        mn0 = fminf(mn0, fminf(fminf(a.x, a.w), fminf(c.z, e.y)));
        mx0 = fmaxf(mx0, fmaxf(fmaxf(a.x, a.w), fmaxf(c.z, e.y)));
        mn1 = fminf(mn1, fminf(fminf(a.y, c.x), fminf(c.w, e.z)));
        mx1 = fmaxf(mx1, fmaxf(fmaxf(a.y, c.x), fmaxf(c.w, e.z)));
        mn2 = fminf(mn2, fminf(fminf(a.z, c.y), fminf(e.x, e.w)));
        mx2 = fmaxf(mx2, fmaxf(fmaxf(a.z, c.y), fmaxf(e.x, e.w)));
    }
    if (sub * 256 < TAIL_G && t0 < TAIL_G) {       // ragged tail: subs 0,1 only
        const int g = FULL_ITERS * STRIDE_G + t0;
        const float4 a = xb[3 * g], c = xb[3 * g + 1], e = xb[3 * g + 2];
        mn0 = fminf(mn0, fminf(fminf(a.x, a.w), fminf(c.z, e.y)));
        mx0 = fmaxf(mx0, fmaxf(fmaxf(a.x, a.w), fmaxf(c.z, e.y)));
        mn1 = fminf(mn1, fminf(fminf(a.y, c.x), fminf(c.w, e.z)));
        mx1 = fmaxf(mx1, fmaxf(fmaxf(a.y, c.x), fmaxf(c.w, e.z)));
        mn2 = fminf(mn2, fminf(fminf(a.z, c.y), fminf(e.x, e.w)));
        mx2 = fmaxf(mx2, fmaxf(fmaxf(a.z, c.y), fmaxf(e.x, e.w)));
    }

    #pragma unroll
    for (int off = 32; off > 0; off >>= 1) {
        mn0 = fminf(mn0, __shfl_down(mn0, off, 64));
        mn1 = fminf(mn1, __shfl_down(mn1, off, 64));
        mn2 = fminf(mn2, __shfl_down(mn2, off, 64));
        mx0 = fmaxf(mx0, __shfl_down(mx0, off, 64));
        mx1 = fmaxf(mx1, __shfl_down(mx1, off, 64));
        mx2 = fmaxf(mx2, __shfl_down(mx2, off, 64));
    }

    __shared__ float smn[4][3], smx[4][3];
    if (lane == 0) {
        smn[wv][0] = mn0; smn[wv][1] = mn1; smn[wv][2] = mn2;
        smx[wv][0] = mx0; smx[wv][1] = mx1; smx[wv][2] = mx2;
    }
    __syncthreads();
    if (threadIdx.x < 3) {
        const int d = threadIdx.x;
        float a = smn[0][d], z = smx[0][d];
        #pragma unroll
        for (int w = 1; w < 4; w++) {
            a = fminf(a, smn[w][d]);
            z = fmaxf(z, smx[w][d]);
        }
        pmin[(b * BPB + sub) * 3 + d] = a;
        pmax[(b * BPB + sub) * 3 + d] = z;
    }
}

// ---------------------------------------------------------------------------
// Kernel 2: ballot-count histogram + fused partial GEMV (atomicAdd to out).
// Re-reads x in REVERSE recency order (tail first, then k=5..0) on the SAME
// XCD as kernel 1 -> LRU-surviving L2 lines are consumed before eviction.
// ---------------------------------------------------------------------------
__global__ __launch_bounds__(256) void hist_gemv_k(const float4* __restrict__ x,
                                                   const float* __restrict__ pmin,
                                                   const float* __restrict__ pmax,
                                                   const float* __restrict__ W,
                                                   const float* __restrict__ bias,
                                                   float* __restrict__ out) {
    const int bid = blockIdx.x;
    const int b = bid & (NB - 1);
    const int sub = bid >> 6;
    const float4* xb = x + (size_t)b * F4_PER_B;
    const int lane = threadIdx.x & 63;
    const int wv = threadIdx.x >> 6;
    const int t0 = sub * 256 + (int)threadIdx.x;

    __shared__ float sW[NVOX * SW_LD];  // transposed [f][c], padded stride 41
    __shared__ float smm[6];            // mn0 mn1 mn2 mx0 mx1 mx2
    __shared__ unsigned swh[4][NVOX];
    __shared__ float fh[NVOX];

    for (int i = threadIdx.x; i < NCLS * NVOX; i += 256)   // overlaps hist loop
        sW[(i % NVOX) * SW_LD + (i / NVOX)] = W[i];

    if (threadIdx.x < 6) {              // reduce the 16 min/max partials
        const int d = threadIdx.x % 3;
        const bool isMax = threadIdx.x >= 3;
        float r = isMax ? -FLT_BIG : FLT_BIG;
        for (int s = 0; s < BPB; s++) {
            float v = isMax ? pmax[(b * BPB + s) * 3 + d]
                            : pmin[(b * BPB + s) * 3 + d];
            r = isMax ? fmaxf(r, v) : fminf(r, v);
        }
        smm[threadIdx.x] = r;
    }
    __syncthreads();
    const float bn0 = smm[0], bn1 = smm[1], bn2 = smm[2];
    const float s40 = (float)VR / (smm[3] - smm[0]);
    const float s41 = (float)VR / (smm[4] - smm[1]);
    const float s42 = (float)VR / (smm[5] - smm[2]);

    unsigned long long ns[6];
    #pragma unroll
    for (int k = 0; k < 6; k++)
        ns[k] = ((lane >> k) & 1) ? 0ull : ~0ull;

    unsigned cnt = 0;
    if (sub * 256 < TAIL_G) {           // tail FIRST (most recent in k1's L2)
        const bool valid = t0 < TAIL_G;
        const unsigned long long vm = __ballot(valid);
        const int g = FULL_ITERS * STRIDE_G + (valid ? t0 : 0);
        const float4 a = xb[3 * g], c = xb[3 * g + 1], e = xb[3 * g + 2];
        int v0 = bin1(a.x, bn0, s40) * 16 + bin1(a.y, bn1, s41) * 4 + bin1(a.z, bn2, s42);
        int v1 = bin1(a.w, bn0, s40) * 16 + bin1(c.x, bn1, s41) * 4 + bin1(c.y, bn2, s42);
        int v2 = bin1(c.z, bn0, s40) * 16 + bin1(c.w, bn1, s41) * 4 + bin1(e.x, bn2, s42);
        int v3 = bin1(e.y, bn0, s40) * 16 + bin1(e.z, bn1, s41) * 4 + bin1(e.w, bn2, s42);
        cnt += (unsigned)__popcll(vm & vox_mask(v0, ns));
        cnt += (unsigned)__popcll(vm & vox_mask(v1, ns));
        cnt += (unsigned)__popcll(vm & vox_mask(v2, ns));
        cnt += (unsigned)__popcll(vm & vox_mask(v3, ns));
    }
    #pragma unroll 2
    for (int k = FULL_ITERS - 1; k >= 0; k--) {    // reverse: recency order
        const int g = t0 + k * STRIDE_G;
        const float4 a = xb[3 * g], c = xb[3 * g + 1], e = xb[3 * g + 2];
        int v0 = bin1(a.x, bn0, s40) * 16 + bin1(a.y, bn1, s41) * 4 + bin1(a.z, bn2, s42);
        int v1 = bin1(a.w, bn0, s40) * 16 + bin1(c.x, bn1, s41) * 4 + bin1(c.y, bn2, s42);
        int v2 = bin1(c.z, bn0, s40) * 16 + bin1(c.w, bn1, s41) * 4 + bin1(e.x, bn2, s42);
        int v3 = bin1(e.y, bn0, s40) * 16 + bin1(e.z, bn1, s41) * 4 + bin1(e.w, bn2, s42);
        cnt += (unsigned)__popcll(vox_mask(v0, ns));
        cnt += (unsigned)__popcll(vox_mask(v1, ns));
        cnt += (unsigned)__popcll(vox_mask(v2, ns));
        cnt += (unsigned)__popcll(vox_mask(v3, ns));
    }

    swh[wv][lane] = cnt;
    __syncthreads();
    if (threadIdx.x < NVOX)
        fh[threadIdx.x] = (float)(swh[0][threadIdx.x] + swh[1][threadIdx.x] +
                                  swh[2][threadIdx.x] + swh[3][threadIdx.x])
                          * (1.0f / (float)NPTS);
    __syncthreads();
    if (threadIdx.x < NCLS) {                      // partial GEMV + atomic sum
        const int c = threadIdx.x;
        float acc = (sub == 0) ? bias[c] : 0.f;
        #pragma unroll
        for (int f = 0; f < NVOX; f++)
            acc += fh[f] * sW[f * SW_LD + c];      // padded: conflict-free
        atomicAdd(&out[b * NCLS + c], acc);
    }
}

extern "C" void kernel_launch(void* const* d_in, const int* in_sizes, int n_in,
                              void* d_out, int out_size, void* d_ws, size_t ws_size,
                              hipStream_t stream) {
    const float4* x = (const float4*)d_in[0];    // (64, 100000, 3) fp32
    const float* W = (const float*)d_in[1];      // (40, 64) fp32
    const float* bias = (const float*)d_in[2];   // (40,) fp32
    float* out = (float*)d_out;                  // (64, 40) fp32

    // ws layout: pmin NBLK*3 f32 | pmax NBLK*3 f32 (fully rewritten per call)
    float* pmin = (float*)d_ws;
    float* pmax = pmin + NBLK * 3;

    minmax_k<<<NBLK, 256, 0, stream>>>(x, pmin, pmax, out);
    hist_gemv_k<<<NBLK, 256, 0, stream>>>(x, pmin, pmax, W, bias, out);
}